// Round 8
// baseline (265.812 us; speedup 1.0000x reference)
//
#include <hip/hip_runtime.h>
#include <math.h>

#define Ss 1024
#define Dd 1024
#define Hh 16
#define Kk 64

typedef __bf16 bf16x8 __attribute__((ext_vector_type(8)));
typedef __bf16 bf16x4 __attribute__((ext_vector_type(4)));
typedef float  f32x4  __attribute__((ext_vector_type(4)));

#define MFMA16(a, b, c) __builtin_amdgcn_mfma_f32_16x16x32_bf16(a, b, c, 0, 0, 0)

// ws element offsets (bf16 units)
#define XB_E   8388608u
#define WT_E   3145728u
#define WOT_E  1048576u
#define QKV_E  8388608u

// Q scale: (1/8) * log2(e) so attn can use raw v_exp_f32 (2^x).
#define QSC 0.18033688011112042f

// v_exp_f32 is natively 2^x; log2(e) is folded into the Q scale in gemm.
__device__ __forceinline__ float exp2_hw(float x) {
    float r; asm("v_exp_f32 %0, %1" : "=v"(r) : "v"(x)); return r;
}

// global -> LDS DMA, 16B per lane. LDS dest: wave-uniform base + lane*16.
typedef __attribute__((address_space(1))) const void gas_void;
typedef __attribute__((address_space(3))) void las_void;
__device__ __forceinline__ void gll16(const __bf16* g, char* l) {
    __builtin_amdgcn_global_load_lds((gas_void*)g, (las_void*)l, 16, 0, 0);
}

// ---------------------------------------------------------------------------
// prep: z<4 -> transpose+cast weight matrix z; z==4 -> cast x to bf16
// ---------------------------------------------------------------------------
__global__ __launch_bounds__(256) void prep(
    const float* __restrict__ x,
    const float* __restrict__ Wq, const float* __restrict__ Wk,
    const float* __restrict__ Wv, const float* __restrict__ Wo,
    __bf16* __restrict__ xb, __bf16* __restrict__ WT, __bf16* __restrict__ WoT)
{
    __shared__ float tile[64][65];
    const int z = blockIdx.z;
    const int t = threadIdx.x;

    if (z == 4) {   // x cast: 256 blocks, 32 rows x 1024 cols each
        size_t blk = blockIdx.y * 16 + blockIdx.x;
        const float4* src = (const float4*)(x + blk * 32768);
        bf16x4* dst = (bf16x4*)(((__bf16*)xb) + blk * 32768);
        #pragma unroll
        for (int u = 0; u < 32; ++u) {
            float4 v = src[u * 256 + t];
            dst[u * 256 + t] =
                (bf16x4){(__bf16)v.x, (__bf16)v.y, (__bf16)v.z, (__bf16)v.w};
        }
        return;
    }

    const float* src = (z == 0) ? Wq : (z == 1) ? Wk : (z == 2) ? Wv : Wo;
    __bf16* dst = (z < 3) ? (WT + (size_t)z * 1048576) : WoT;

    int r0 = blockIdx.y * 64, c0 = blockIdx.x * 64;
    int rr = t >> 2, cg = (t & 3) * 16;

    #pragma unroll
    for (int u = 0; u < 4; ++u) {
        float4 v = *(const float4*)(src + (size_t)(r0 + rr) * 1024 + c0 + cg + u * 4);
        tile[rr][cg + u * 4 + 0] = v.x;
        tile[rr][cg + u * 4 + 1] = v.y;
        tile[rr][cg + u * 4 + 2] = v.z;
        tile[rr][cg + u * 4 + 3] = v.w;
    }
    __syncthreads();
    bf16x8 o0, o1;
    #pragma unroll
    for (int jj = 0; jj < 8; ++jj) o0[jj] = (__bf16)tile[cg + jj][rr];
    #pragma unroll
    for (int jj = 0; jj < 8; ++jj) o1[jj] = (__bf16)tile[cg + 8 + jj][rr];
    __bf16* dp = dst + (size_t)(c0 + rr) * 1024 + r0 + cg;
    *(bf16x8*)dp = o0;
    *(bf16x8*)(dp + 8) = o1;
}

// ---------------------------------------------------------------------------
// QKV GEMM: R5's measured-best kernel, restored VERBATIM (74.6 us).
// BM=BN=256, BK=64, 512 thr (2Mx4N waves), 128x64/wave, acc[8][4].
// Coarse 3-barrier schedule: vmcnt(8) counted at iter top (tile it+1's 8
// DMAs stay in flight across B1), stage tile it+2 at B3 after lgkm drain.
// T2 XOR swizzle (conflicts 0), bijective XCD swizzle (384 blocks).
// ---------------------------------------------------------------------------
__global__ __launch_bounds__(512, 2) void gemm_qkv(
    const __bf16* __restrict__ A, const __bf16* __restrict__ Bt, int mode,
    __bf16* __restrict__ qb, __bf16* __restrict__ kb, __bf16* __restrict__ vb,
    const float* __restrict__ bq, const float* __restrict__ bk,
    const float* __restrict__ bv,
    float* __restrict__ outf, const float* __restrict__ bo)
{
    __shared__ __align__(16) __bf16 As[2][256][64];   // 64 KB
    __shared__ __align__(16) __bf16 Bs[2][256][64];   // 64 KB

    const int t = threadIdx.x;
    const int wave = t >> 6, lane = t & 63;
    const int quad = lane >> 4, l16 = lane & 15;
    const int wm = wave >> 2, wn = wave & 3;          // 2M x 4N waves

    const int nwg = gridDim.x * gridDim.y;
    const int cpx = nwg >> 3;
    int g = blockIdx.y * gridDim.x + blockIdx.x;
    g = (g & 7) * cpx + (g >> 3);
    const int bx = g % gridDim.x, by = g / gridDim.x;
    const int m0 = by * 256, n0 = bx * 256;

    const int srow = t >> 3;                              // 0..63
    const int scol = (((t & 7) ^ (srow & 7)) * 8);        // elems
    const __bf16* pa = A  + (size_t)(m0 + srow) * 1024 + scol;
    const __bf16* pb = Bt + (size_t)(n0 + srow) * 1024 + scol;
    char* lA = (char*)(&As[0][0][0]) + t * 16;
    char* lB = (char*)(&Bs[0][0][0]) + t * 16;

#define STAGE(slot, k0) do {                                     \
        gll16(pa + (k0),           lA + (slot) * 32768);         \
        gll16(pa + (k0) +  65536,  lA + (slot) * 32768 +  8192); \
        gll16(pa + (k0) + 131072,  lA + (slot) * 32768 + 16384); \
        gll16(pa + (k0) + 196608,  lA + (slot) * 32768 + 24576); \
        gll16(pb + (k0),           lB + (slot) * 32768);         \
        gll16(pb + (k0) +  65536,  lB + (slot) * 32768 +  8192); \
        gll16(pb + (k0) + 131072,  lB + (slot) * 32768 + 16384); \
        gll16(pb + (k0) + 196608,  lB + (slot) * 32768 + 24576); \
    } while (0)

    STAGE(0, 0);     // tile 0 -> slot 0   (8 DMAs/wave)
    STAGE(1, 64);    // tile 1 -> slot 1   (16 outstanding)

    f32x4 acc[8][4];
    #pragma unroll
    for (int i = 0; i < 8; ++i)
        #pragma unroll
        for (int j = 0; j < 4; ++j) acc[i][j] = (f32x4){0.f, 0.f, 0.f, 0.f};

    const int swz = (l16 & 7) << 4;   // read-side XOR (row&7 == l16&7)

    for (int it = 0; it < 16; ++it) {
        const int s = it & 1;
        if (it == 15) asm volatile("s_waitcnt vmcnt(0)" ::: "memory");
        else          asm volatile("s_waitcnt vmcnt(8)" ::: "memory");
        __builtin_amdgcn_s_barrier();                 // B1

        const char* baseA = (const char*)&As[s][0][0];
        const char* baseB = (const char*)&Bs[s][0][0];

        bf16x8 bfrag[2][4];
        #pragma unroll
        for (int nj = 0; nj < 4; ++nj) {
            int rowb = (wn * 64 + nj * 16 + l16) * 128;
            bfrag[0][nj] = *(const bf16x8*)(baseB + rowb + ((quad * 16) ^ swz));
            bfrag[1][nj] = *(const bf16x8*)(baseB + rowb + ((64 + quad * 16) ^ swz));
        }

        // ---- phase A: mi 0..3 ----
        {
            bf16x8 afr[4][2];
            #pragma unroll
            for (int mi = 0; mi < 4; ++mi) {
                int rowa = (wm * 128 + mi * 16 + l16) * 128;
                afr[mi][0] = *(const bf16x8*)(baseA + rowa + ((quad * 16) ^ swz));
                afr[mi][1] = *(const bf16x8*)(baseA + rowa + ((64 + quad * 16) ^ swz));
            }
            __builtin_amdgcn_s_setprio(1);
            #pragma unroll
            for (int mi = 0; mi < 4; ++mi)
                #pragma unroll
                for (int nj = 0; nj < 4; ++nj)
                    acc[mi][nj] = MFMA16(afr[mi][1], bfrag[1][nj],
                                  MFMA16(afr[mi][0], bfrag[0][nj], acc[mi][nj]));
            __builtin_amdgcn_s_setprio(0);
        }
        __builtin_amdgcn_s_barrier();                 // B2 (rhythm)

        // ---- phase B: mi 4..7 ----
        {
            bf16x8 afr[4][2];
            #pragma unroll
            for (int mi = 0; mi < 4; ++mi) {
                int rowa = (wm * 128 + (mi + 4) * 16 + l16) * 128;
                afr[mi][0] = *(const bf16x8*)(baseA + rowa + ((quad * 16) ^ swz));
                afr[mi][1] = *(const bf16x8*)(baseA + rowa + ((64 + quad * 16) ^ swz));
            }
            asm volatile("s_waitcnt lgkmcnt(0)" ::: "memory");
            __builtin_amdgcn_sched_barrier(0);
            __builtin_amdgcn_s_barrier();             // B3
            if (it < 14) STAGE(s, (it + 2) * 64);

            __builtin_amdgcn_s_setprio(1);
            #pragma unroll
            for (int mi = 0; mi < 4; ++mi)
                #pragma unroll
                for (int nj = 0; nj < 4; ++nj)
                    acc[mi + 4][nj] = MFMA16(afr[mi][1], bfrag[1][nj],
                                      MFMA16(afr[mi][0], bfrag[0][nj], acc[mi + 4][nj]));
            __builtin_amdgcn_s_setprio(0);
        }
    }
#undef STAGE

    if (mode == 0) {
        const int z = n0 >> 10;   // 256-tiles never straddle 1024 boundaries
        const float* bias = (z == 0) ? bq : (z == 1) ? bk : bv;
        const float sc2 = (z == 0) ? QSC : 1.0f;
        #pragma unroll
        for (int mi = 0; mi < 8; ++mi) {
            int row = m0 + wm * 128 + mi * 16 + quad * 4;
            int b = row >> 10, sx = row & 1023;
            #pragma unroll
            for (int nj = 0; nj < 4; ++nj) {
                int n1 = (n0 + wn * 64 + nj * 16 + l16) & 1023;
                int h = n1 >> 6, ch = n1 & 63;
                float bia = bias[n1];
                if (z < 2) {
                    __bf16* dst = ((z == 0) ? qb : kb)
                        + ((size_t)(b * Hh + h) * Ss + sx) * Kk + ch;
                    #pragma unroll
                    for (int r = 0; r < 4; ++r)
                        dst[(size_t)r * Kk] = (__bf16)((acc[mi][nj][r] + bia) * sc2);
                } else {
                    float bia2 = bv[n1];
                    bf16x4 o;
                    #pragma unroll
                    for (int r = 0; r < 4; ++r) o[r] = (__bf16)(acc[mi][nj][r] + bia2);
                    *(bf16x4*)(vb + ((size_t)(b * Hh + h) * Kk + ch) * Ss + sx) = o;
                }
            }
        }
    } else {
        #pragma unroll
        for (int mi = 0; mi < 8; ++mi) {
            int row = m0 + wm * 128 + mi * 16 + quad * 4;
            #pragma unroll
            for (int nj = 0; nj < 4; ++nj) {
                int n = n0 + wn * 64 + nj * 16 + l16;
                float bia = bo[n];
                #pragma unroll
                for (int r = 0; r < 4; ++r)
                    outf[(size_t)(row + r) * 1024 + n] = acc[mi][nj][r] + bia;
            }
        }
    }
}

// ---------------------------------------------------------------------------
// Out-GEMM: OCCUPANCY-FIRST redesign. BM=BN=128, BK=64, 256 thr (4 waves
// 2Mx2N, 64x64/wave, acc[4][4]=64 regs). LDS 64 KB -> 2 blocks/CU; grid
// 8x64 = 512 blocks = ALL co-resident in one round. Two independent block
// pipelines per CU stagger their fill stalls (m97/m114 mechanism) -- the
// axis every 256^2/512-thr variant was locked out of (1 block/CU).
// Same coarse schedule: vmcnt(8) counted, stage it+2 at B3 after lgkm drain.
// ---------------------------------------------------------------------------
__global__ __launch_bounds__(256, 2) void gemm_out(
    const __bf16* __restrict__ A, const __bf16* __restrict__ Bt,
    float* __restrict__ outf, const float* __restrict__ bo)
{
    __shared__ __align__(16) __bf16 As[2][128][64];   // 32 KB
    __shared__ __align__(16) __bf16 Bs[2][128][64];   // 32 KB

    const int t = threadIdx.x;
    const int wave = t >> 6, lane = t & 63;
    const int quad = lane >> 4, l16 = lane & 15;
    const int wm = wave >> 1, wn = wave & 1;          // 2M x 2N waves

    // Bijective XCD swizzle (nwg=512, cpx=64).
    int g = blockIdx.y * gridDim.x + blockIdx.x;
    g = (g & 7) * 64 + (g >> 3);
    const int bx = g % gridDim.x, by = g / gridDim.x;
    const int m0 = by * 128, n0 = bx * 128;

    const int srow = t >> 3;                              // 0..31
    const int scol = (((t & 7) ^ (srow & 7)) * 8);        // elems
    const __bf16* pa = A  + (size_t)(m0 + srow) * 1024 + scol;
    const __bf16* pb = Bt + (size_t)(n0 + srow) * 1024 + scol;
    char* lA = (char*)(&As[0][0][0]) + t * 16;
    char* lB = (char*)(&Bs[0][0][0]) + t * 16;

    // chunk c = rows [32c, 32c+32); 4 chunks each for A and B = 8 DMAs/tile.
#define STAGE2(slot, k0) do {                                                 \
        _Pragma("unroll")                                                     \
        for (int c_ = 0; c_ < 4; ++c_)                                        \
            gll16(pa + (k0) + c_ * 32768, lA + (slot) * 16384 + c_ * 4096);   \
        _Pragma("unroll")                                                     \
        for (int c_ = 0; c_ < 4; ++c_)                                        \
            gll16(pb + (k0) + c_ * 32768, lB + (slot) * 16384 + c_ * 4096);   \
    } while (0)

    STAGE2(0, 0);
    STAGE2(1, 64);

    f32x4 acc[4][4];
    #pragma unroll
    for (int i = 0; i < 4; ++i)
        #pragma unroll
        for (int j = 0; j < 4; ++j) acc[i][j] = (f32x4){0.f, 0.f, 0.f, 0.f};

    const int swz = (l16 & 7) << 4;

    for (int it = 0; it < 16; ++it) {
        const int s = it & 1;
        if (it == 15) asm volatile("s_waitcnt vmcnt(0)" ::: "memory");
        else          asm volatile("s_waitcnt vmcnt(8)" ::: "memory");
        __builtin_amdgcn_s_barrier();                 // B1

        const char* baseA = (const char*)&As[s][0][0];
        const char* baseB = (const char*)&Bs[s][0][0];

        bf16x8 bfr[4][2];
        #pragma unroll
        for (int nj = 0; nj < 4; ++nj) {
            int rb = (wn * 64 + nj * 16 + l16) * 128;
            bfr[nj][0] = *(const bf16x8*)(baseB + rb + ((quad * 16) ^ swz));
            bfr[nj][1] = *(const bf16x8*)(baseB + rb + ((64 + quad * 16) ^ swz));
        }

        // ---- phase A: mi 0..1 ----
        {
            bf16x8 afr[2][2];
            #pragma unroll
            for (int mi = 0; mi < 2; ++mi) {
                int ra = (wm * 64 + mi * 16 + l16) * 128;
                afr[mi][0] = *(const bf16x8*)(baseA + ra + ((quad * 16) ^ swz));
                afr[mi][1] = *(const bf16x8*)(baseA + ra + ((64 + quad * 16) ^ swz));
            }
            __builtin_amdgcn_s_setprio(1);
            #pragma unroll
            for (int mi = 0; mi < 2; ++mi)
                #pragma unroll
                for (int nj = 0; nj < 4; ++nj)
                    acc[mi][nj] = MFMA16(afr[mi][1], bfr[nj][1],
                                  MFMA16(afr[mi][0], bfr[nj][0], acc[mi][nj]));
            __builtin_amdgcn_s_setprio(0);
        }
        __builtin_amdgcn_s_barrier();                 // B2 (rhythm)

        // ---- phase B: mi 2..3 ----
        {
            bf16x8 afr[2][2];
            #pragma unroll
            for (int mi = 0; mi < 2; ++mi) {
                int ra = (wm * 64 + (mi + 2) * 16 + l16) * 128;
                afr[mi][0] = *(const bf16x8*)(baseA + ra + ((quad * 16) ^ swz));
                afr[mi][1] = *(const bf16x8*)(baseA + ra + ((64 + quad * 16) ^ swz));
            }
            asm volatile("s_waitcnt lgkmcnt(0)" ::: "memory");
            __builtin_amdgcn_sched_barrier(0);
            __builtin_amdgcn_s_barrier();             // B3
            if (it < 14) STAGE2(s, (it + 2) * 64);

            __builtin_amdgcn_s_setprio(1);
            #pragma unroll
            for (int mi = 0; mi < 2; ++mi)
                #pragma unroll
                for (int nj = 0; nj < 4; ++nj)
                    acc[mi + 2][nj] = MFMA16(afr[mi][1], bfr[nj][1],
                                      MFMA16(afr[mi][0], bfr[nj][0], acc[mi + 2][nj]));
            __builtin_amdgcn_s_setprio(0);
        }
    }
#undef STAGE2

    #pragma unroll
    for (int mi = 0; mi < 4; ++mi) {
        int row = m0 + wm * 64 + mi * 16 + quad * 4;
        #pragma unroll
        for (int nj = 0; nj < 4; ++nj) {
            int n = n0 + wn * 64 + nj * 16 + l16;
            float bia = bo[n];
            #pragma unroll
            for (int r = 0; r < 4; ++r)
                outf[(size_t)(row + r) * 1024 + n] = acc[mi][nj][r] + bia;
        }
    }
}

// ---------------------------------------------------------------------------
// Flash attention: fixed-base softmax (scores bounded => no max tracking),
// wave-private P (no barrier), 32 q/wave, VGPR prefetch of next K/V tile,
// ping-pong K/V LDS (one barrier per tile), exp2 softmax, setprio on MFMA.
// Mask: p = mq ? (mk ? exp(s) : 0) : 1 — exactly matches reference semantics.
// ---------------------------------------------------------------------------
__global__ __launch_bounds__(256) void attn(
    const __bf16* __restrict__ qb, const __bf16* __restrict__ kb,
    const __bf16* __restrict__ vb, const int* __restrict__ mask,
    __bf16* __restrict__ ctx)
{
    const int bh = blockIdx.x;
    const int q0 = blockIdx.y * 128;
    const int b  = bh >> 4;
    const int h  = bh & 15;
    const size_t base = (size_t)bh * Ss * Kk;

    __shared__ __align__(16) __bf16 Qs[128][72];
    __shared__ __align__(16) __bf16 Ks[2][64][72];
    __shared__ __align__(16) __bf16 VTs[2][64][72];
    __shared__ __align__(16) __bf16 Ps[4][32][72];
    __shared__ float mkf[1024];

    const int t    = threadIdx.x;
    const int wave = t >> 6, lane = t & 63;
    const int quad = lane >> 4, l16 = lane & 15;
    const int qbase = wave * 32;

    #pragma unroll
    for (int p = 0; p < 4; ++p) {
        int idx = t + p * 256;
        int r = idx >> 3, g = idx & 7;
        *(bf16x8*)&Qs[r][g * 8] =
            *(const bf16x8*)(qb + base + (size_t)(q0 + r) * Kk + g * 8);
    }
    {
        int4 mi = *(const int4*)(mask + b * Ss + t * 4);
        mkf[t * 4 + 0] = (float)mi.x;
        mkf[t * 4 + 1] = (float)mi.y;
        mkf[t * 4 + 2] = (float)mi.z;
        mkf[t * 4 + 3] = (float)mi.w;
    }

    const int r0 = t >> 3, c0 = (t & 7) * 8;
    bf16x8 kr0, kr1, vr0, vr1;
    kr0 = *(const bf16x8*)(kb + base + (size_t)(r0) * Kk + c0);
    kr1 = *(const bf16x8*)(kb + base + (size_t)(r0 + 32) * Kk + c0);
    vr0 = *(const bf16x8*)(vb + base + (size_t)(r0) * Ss + c0);
    vr1 = *(const bf16x8*)(vb + base + (size_t)(r0 + 32) * Ss + c0);

    __syncthreads();   // Qs + mkf visible

    bf16x8 aq[2][2];
    #pragma unroll
    for (int rg = 0; rg < 2; ++rg) {
        aq[rg][0] = *(const bf16x8*)&Qs[qbase + rg * 16 + l16][quad * 8];
        aq[rg][1] = *(const bf16x8*)&Qs[qbase + rg * 16 + l16][32 + quad * 8];
    }
    float mqf[2][4], omqf[2][4];
    #pragma unroll
    for (int rg = 0; rg < 2; ++rg)
        #pragma unroll
        for (int i = 0; i < 4; ++i) {
            float m = mkf[q0 + qbase + rg * 16 + quad * 4 + i];
            mqf[rg][i] = m; omqf[rg][i] = 1.0f - m;
        }

    f32x4 O[2][4];
    float lsum[2][4];
    #pragma unroll
    for (int rg = 0; rg < 2; ++rg)
        #pragma unroll
        for (int nb = 0; nb < 4; ++nb) O[rg][nb] = (f32x4){0.f, 0.f, 0.f, 0.f};
    #pragma unroll
    for (int rg = 0; rg < 2; ++rg)
        #pragma unroll
        for (int i = 0; i < 4; ++i) lsum[rg][i] = 0.f;

    for (int kt = 0; kt < Ss; kt += 64) {
        const int p = (kt >> 6) & 1;
        *(bf16x8*)&Ks[p][r0][c0] = kr0;
        *(bf16x8*)&Ks[p][r0 + 32][c0] = kr1;
        *(bf16x8*)&VTs[p][r0][c0] = vr0;
        *(bf16x8*)&VTs[p][r0 + 32][c0] = vr1;
        __syncthreads();   // the ONLY barrier per tile

        int ktn = kt + 64;
        if (ktn < Ss) {    // issue next tile's loads; in flight across compute
            kr0 = *(const bf16x8*)(kb + base + (size_t)(ktn + r0) * Kk + c0);
            kr1 = *(const bf16x8*)(kb + base + (size_t)(ktn + r0 + 32) * Kk + c0);
            vr0 = *(const bf16x8*)(vb + base + (size_t)(r0) * Ss + ktn + c0);
            vr1 = *(const bf16x8*)(vb + base + (size_t)(r0 + 32) * Ss + ktn + c0);
        }

        float mkv[4];
        #pragma unroll
        for (int nb = 0; nb < 4; ++nb) mkv[nb] = mkf[kt + nb * 16 + l16];

        bf16x8 kb0[4], kb1[4];
        #pragma unroll
        for (int nb = 0; nb < 4; ++nb) {
            kb0[nb] = *(const bf16x8*)&Ks[p][nb * 16 + l16][quad * 8];
            kb1[nb] = *(const bf16x8*)&Ks[p][nb * 16 + l16][32 + quad * 8];
        }

        f32x4 s[2][4];
        __builtin_amdgcn_s_setprio(1);
        #pragma unroll
        for (int rg = 0; rg < 2; ++rg)
            #pragma unroll
            for (int nb = 0; nb < 4; ++nb) {
                f32x4 a = (f32x4){0.f, 0.f, 0.f, 0.f};
                a = MFMA16(aq[rg][0], kb0[nb], a);
                a = MFMA16(aq[rg][1], kb1[nb], a);
                s[rg][nb] = a;
            }
        __builtin_amdgcn_s_setprio(0);

        #pragma unroll
        for (int rg = 0; rg < 2; ++rg)
            #pragma unroll
            for (int i = 0; i < 4; ++i) {
                float ls = 0.f;
                #pragma unroll
                for (int nb = 0; nb < 4; ++nb) {
                    float pv = exp2_hw(s[rg][nb][i]) * mkv[nb];
                    pv = pv * mqf[rg][i] + omqf[rg][i];
                    Ps[wave][rg * 16 + quad * 4 + i][nb * 16 + l16] = (__bf16)pv;
                    ls += pv;
                }
                lsum[rg][i] += ls;
            }

        bf16x8 ap0[2], ap1[2];
        #pragma unroll
        for (int rg = 0; rg < 2; ++rg) {
            ap0[rg] = *(const bf16x8*)&Ps[wave][rg * 16 + l16][quad * 8];
            ap1[rg] = *(const bf16x8*)&Ps[wave][rg * 16 + l16][32 + quad * 8];
        }
        __builtin_amdgcn_s_setprio(1);
        #pragma unroll
        for (int nb = 0; nb < 4; ++nb) {
            bf16x8 vb0 = *(const bf16x8*)&VTs[p][nb * 16 + l16][quad * 8];
            bf16x8 vb1 = *(const bf16x8*)&VTs[p][nb * 16 + l16][32 + quad * 8];
            #pragma unroll
            for (int rg = 0; rg < 2; ++rg) {
                O[rg][nb] = MFMA16(ap0[rg], vb0, O[rg][nb]);
                O[rg][nb] = MFMA16(ap1[rg], vb1, O[rg][nb]);
            }
        }
        __builtin_amdgcn_s_setprio(0);
    }

    #pragma unroll
    for (int rg = 0; rg < 2; ++rg)
        #pragma unroll
        for (int i = 0; i < 4; ++i) {
            float l = lsum[rg][i];
            l += __shfl_xor(l, 1);
            l += __shfl_xor(l, 2);
            l += __shfl_xor(l, 4);
            l += __shfl_xor(l, 8);
            float inv = 1.0f / l;
            int srow = q0 + qbase + rg * 16 + quad * 4 + i;
            __bf16* dst = ctx + ((size_t)(b * Ss + srow) * Hh + h) * Kk;
            #pragma unroll
            for (int nb = 0; nb < 4; ++nb)
                dst[nb * 16 + l16] = (__bf16)(O[rg][nb][i] * inv);
        }
}

extern "C" void kernel_launch(void* const* d_in, const int* in_sizes, int n_in,
                              void* d_out, int out_size, void* d_ws, size_t ws_size,
                              hipStream_t stream) {
    const float* x    = (const float*)d_in[0];
    const int*   mask = (const int*)d_in[1];
    const float* Wq   = (const float*)d_in[2];
    const float* bq   = (const float*)d_in[3];
    const float* Wk   = (const float*)d_in[4];
    const float* bk   = (const float*)d_in[5];
    const float* Wv   = (const float*)d_in[6];
    const float* bv   = (const float*)d_in[7];
    const float* Wo   = (const float*)d_in[8];
    const float* bo   = (const float*)d_in[9];

    __bf16* xb   = (__bf16*)d_ws;
    __bf16* WT   = xb + XB_E;
    __bf16* WoT  = WT + WT_E;
    __bf16* qb   = WoT + WOT_E;
    __bf16* kb   = qb + QKV_E;
    __bf16* vb   = kb + QKV_E;
    __bf16* ctxb = vb + QKV_E;
    float* out = (float*)d_out;

    prep<<<dim3(16, 16, 5), 256, 0, stream>>>(x, Wq, Wk, Wv, Wo, xb, WT, WoT);
    gemm_qkv<<<dim3(12, 32), 512, 0, stream>>>(xb, WT, 0, qb, kb, vb,
                                               bq, bk, bv, nullptr, nullptr);
    attn<<<dim3(128, 8), 256, 0, stream>>>(qb, kb, vb, mask, ctxb);
    gemm_out<<<dim3(8, 64), 256, 0, stream>>>(ctxb, WoT, out, bo);
}

// Round 9
// 259.832 us; speedup vs baseline: 1.0230x; 1.0230x over previous
//
#include <hip/hip_runtime.h>
#include <math.h>

#define Ss 1024
#define Dd 1024
#define Hh 16
#define Kk 64

typedef __bf16 bf16x8 __attribute__((ext_vector_type(8)));
typedef __bf16 bf16x4 __attribute__((ext_vector_type(4)));
typedef float  f32x4  __attribute__((ext_vector_type(4)));

#define MFMA16(a, b, c) __builtin_amdgcn_mfma_f32_16x16x32_bf16(a, b, c, 0, 0, 0)

// ws element offsets (bf16 units)
#define XB_E   8388608u
#define WT_E   3145728u
#define WOT_E  1048576u
#define QKV_E  8388608u

// Q scale: (1/8) * log2(e) so attn can use raw v_exp_f32 (2^x).
#define QSC 0.18033688011112042f

// v_exp_f32 is natively 2^x; log2(e) is folded into the Q scale in gemm.
__device__ __forceinline__ float exp2_hw(float x) {
    float r; asm("v_exp_f32 %0, %1" : "=v"(r) : "v"(x)); return r;
}

// global -> LDS DMA, 16B per lane. LDS dest: wave-uniform base + lane*16.
typedef __attribute__((address_space(1))) const void gas_void;
typedef __attribute__((address_space(3))) void las_void;
__device__ __forceinline__ void gll16(const __bf16* g, char* l) {
    __builtin_amdgcn_global_load_lds((gas_void*)g, (las_void*)l, 16, 0, 0);
}

// ---------------------------------------------------------------------------
// prep: z<4 -> transpose+cast weight matrix z; z==4 -> cast x to bf16
// ---------------------------------------------------------------------------
__global__ __launch_bounds__(256) void prep(
    const float* __restrict__ x,
    const float* __restrict__ Wq, const float* __restrict__ Wk,
    const float* __restrict__ Wv, const float* __restrict__ Wo,
    __bf16* __restrict__ xb, __bf16* __restrict__ WT, __bf16* __restrict__ WoT)
{
    __shared__ float tile[64][65];
    const int z = blockIdx.z;
    const int t = threadIdx.x;

    if (z == 4) {   // x cast: 256 blocks, 32 rows x 1024 cols each
        size_t blk = blockIdx.y * 16 + blockIdx.x;
        const float4* src = (const float4*)(x + blk * 32768);
        bf16x4* dst = (bf16x4*)(((__bf16*)xb) + blk * 32768);
        #pragma unroll
        for (int u = 0; u < 32; ++u) {
            float4 v = src[u * 256 + t];
            dst[u * 256 + t] =
                (bf16x4){(__bf16)v.x, (__bf16)v.y, (__bf16)v.z, (__bf16)v.w};
        }
        return;
    }

    const float* src = (z == 0) ? Wq : (z == 1) ? Wk : (z == 2) ? Wv : Wo;
    __bf16* dst = (z < 3) ? (WT + (size_t)z * 1048576) : WoT;

    int r0 = blockIdx.y * 64, c0 = blockIdx.x * 64;
    int rr = t >> 2, cg = (t & 3) * 16;

    #pragma unroll
    for (int u = 0; u < 4; ++u) {
        float4 v = *(const float4*)(src + (size_t)(r0 + rr) * 1024 + c0 + cg + u * 4);
        tile[rr][cg + u * 4 + 0] = v.x;
        tile[rr][cg + u * 4 + 1] = v.y;
        tile[rr][cg + u * 4 + 2] = v.z;
        tile[rr][cg + u * 4 + 3] = v.w;
    }
    __syncthreads();
    bf16x8 o0, o1;
    #pragma unroll
    for (int jj = 0; jj < 8; ++jj) o0[jj] = (__bf16)tile[cg + jj][rr];
    #pragma unroll
    for (int jj = 0; jj < 8; ++jj) o1[jj] = (__bf16)tile[cg + 8 + jj][rr];
    __bf16* dp = dst + (size_t)(c0 + rr) * 1024 + r0 + cg;
    *(bf16x8*)dp = o0;
    *(bf16x8*)(dp + 8) = o1;
}

// ---------------------------------------------------------------------------
// QKV GEMM: measured-best (74.6-76.6 us), BANKED — do not touch.
// BM=BN=256, BK=64, 512 thr (2Mx4N waves), 128x64/wave, acc[8][4].
// Coarse 3-barrier schedule: vmcnt(8) counted at iter top (tile it+1's 8
// DMAs stay in flight across B1), stage tile it+2 at B3 after lgkm drain.
// Deep cover needed: QKV panels (8MB/XCD) spill L2 -> L3 latency ~600-900cy.
// ---------------------------------------------------------------------------
__global__ __launch_bounds__(512, 2) void gemm_qkv(
    const __bf16* __restrict__ A, const __bf16* __restrict__ Bt,
    __bf16* __restrict__ qb, __bf16* __restrict__ kb, __bf16* __restrict__ vb,
    const float* __restrict__ bq, const float* __restrict__ bk,
    const float* __restrict__ bv)
{
    __shared__ __align__(16) __bf16 As[2][256][64];   // 64 KB
    __shared__ __align__(16) __bf16 Bs[2][256][64];   // 64 KB

    const int t = threadIdx.x;
    const int wave = t >> 6, lane = t & 63;
    const int quad = lane >> 4, l16 = lane & 15;
    const int wm = wave >> 2, wn = wave & 3;          // 2M x 4N waves

    const int nwg = gridDim.x * gridDim.y;
    const int cpx = nwg >> 3;
    int g = blockIdx.y * gridDim.x + blockIdx.x;
    g = (g & 7) * cpx + (g >> 3);
    const int bx = g % gridDim.x, by = g / gridDim.x;
    const int m0 = by * 256, n0 = bx * 256;

    const int srow = t >> 3;                              // 0..63
    const int scol = (((t & 7) ^ (srow & 7)) * 8);        // elems
    const __bf16* pa = A  + (size_t)(m0 + srow) * 1024 + scol;
    const __bf16* pb = Bt + (size_t)(n0 + srow) * 1024 + scol;
    char* lA = (char*)(&As[0][0][0]) + t * 16;
    char* lB = (char*)(&Bs[0][0][0]) + t * 16;

#define STAGE(slot, k0) do {                                     \
        gll16(pa + (k0),           lA + (slot) * 32768);         \
        gll16(pa + (k0) +  65536,  lA + (slot) * 32768 +  8192); \
        gll16(pa + (k0) + 131072,  lA + (slot) * 32768 + 16384); \
        gll16(pa + (k0) + 196608,  lA + (slot) * 32768 + 24576); \
        gll16(pb + (k0),           lB + (slot) * 32768);         \
        gll16(pb + (k0) +  65536,  lB + (slot) * 32768 +  8192); \
        gll16(pb + (k0) + 131072,  lB + (slot) * 32768 + 16384); \
        gll16(pb + (k0) + 196608,  lB + (slot) * 32768 + 24576); \
    } while (0)

    STAGE(0, 0);     // tile 0 -> slot 0   (8 DMAs/wave)
    STAGE(1, 64);    // tile 1 -> slot 1   (16 outstanding)

    f32x4 acc[8][4];
    #pragma unroll
    for (int i = 0; i < 8; ++i)
        #pragma unroll
        for (int j = 0; j < 4; ++j) acc[i][j] = (f32x4){0.f, 0.f, 0.f, 0.f};

    const int swz = (l16 & 7) << 4;   // read-side XOR (row&7 == l16&7)

    for (int it = 0; it < 16; ++it) {
        const int s = it & 1;
        if (it == 15) asm volatile("s_waitcnt vmcnt(0)" ::: "memory");
        else          asm volatile("s_waitcnt vmcnt(8)" ::: "memory");
        __builtin_amdgcn_s_barrier();                 // B1

        const char* baseA = (const char*)&As[s][0][0];
        const char* baseB = (const char*)&Bs[s][0][0];

        bf16x8 bfrag[2][4];
        #pragma unroll
        for (int nj = 0; nj < 4; ++nj) {
            int rowb = (wn * 64 + nj * 16 + l16) * 128;
            bfrag[0][nj] = *(const bf16x8*)(baseB + rowb + ((quad * 16) ^ swz));
            bfrag[1][nj] = *(const bf16x8*)(baseB + rowb + ((64 + quad * 16) ^ swz));
        }

        // ---- phase A: mi 0..3 ----
        {
            bf16x8 afr[4][2];
            #pragma unroll
            for (int mi = 0; mi < 4; ++mi) {
                int rowa = (wm * 128 + mi * 16 + l16) * 128;
                afr[mi][0] = *(const bf16x8*)(baseA + rowa + ((quad * 16) ^ swz));
                afr[mi][1] = *(const bf16x8*)(baseA + rowa + ((64 + quad * 16) ^ swz));
            }
            __builtin_amdgcn_s_setprio(1);
            #pragma unroll
            for (int mi = 0; mi < 4; ++mi)
                #pragma unroll
                for (int nj = 0; nj < 4; ++nj)
                    acc[mi][nj] = MFMA16(afr[mi][1], bfrag[1][nj],
                                  MFMA16(afr[mi][0], bfrag[0][nj], acc[mi][nj]));
            __builtin_amdgcn_s_setprio(0);
        }
        __builtin_amdgcn_s_barrier();                 // B2 (rhythm)

        // ---- phase B: mi 4..7 ----
        {
            bf16x8 afr[4][2];
            #pragma unroll
            for (int mi = 0; mi < 4; ++mi) {
                int rowa = (wm * 128 + (mi + 4) * 16 + l16) * 128;
                afr[mi][0] = *(const bf16x8*)(baseA + rowa + ((quad * 16) ^ swz));
                afr[mi][1] = *(const bf16x8*)(baseA + rowa + ((64 + quad * 16) ^ swz));
            }
            asm volatile("s_waitcnt lgkmcnt(0)" ::: "memory");
            __builtin_amdgcn_sched_barrier(0);
            __builtin_amdgcn_s_barrier();             // B3
            if (it < 14) STAGE(s, (it + 2) * 64);

            __builtin_amdgcn_s_setprio(1);
            #pragma unroll
            for (int mi = 0; mi < 4; ++mi)
                #pragma unroll
                for (int nj = 0; nj < 4; ++nj)
                    acc[mi + 4][nj] = MFMA16(afr[mi][1], bfrag[1][nj],
                                      MFMA16(afr[mi][0], bfrag[0][nj], acc[mi + 4][nj]));
            __builtin_amdgcn_s_setprio(0);
        }
    }
#undef STAGE

    {
        const int z = n0 >> 10;   // 256-tiles never straddle 1024 boundaries
        const float* bias = (z == 0) ? bq : (z == 1) ? bk : bv;
        const float sc2 = (z == 0) ? QSC : 1.0f;
        #pragma unroll
        for (int mi = 0; mi < 8; ++mi) {
            int row = m0 + wm * 128 + mi * 16 + quad * 4;
            int b = row >> 10, sx = row & 1023;
            #pragma unroll
            for (int nj = 0; nj < 4; ++nj) {
                int n1 = (n0 + wn * 64 + nj * 16 + l16) & 1023;
                int h = n1 >> 6, ch = n1 & 63;
                float bia = bias[n1];
                if (z < 2) {
                    __bf16* dst = ((z == 0) ? qb : kb)
                        + ((size_t)(b * Hh + h) * Ss + sx) * Kk + ch;
                    #pragma unroll
                    for (int r = 0; r < 4; ++r)
                        dst[(size_t)r * Kk] = (__bf16)((acc[mi][nj][r] + bia) * sc2);
                } else {
                    float bia2 = bv[n1];
                    bf16x4 o;
                    #pragma unroll
                    for (int r = 0; r < 4; ++r) o[r] = (__bf16)(acc[mi][nj][r] + bia2);
                    *(bf16x4*)(vb + ((size_t)(b * Hh + h) * Kk + ch) * Ss + sx) = o;
                }
            }
        }
    }
}

// ---------------------------------------------------------------------------
// Out-GEMM: R7's fine-grained 2-phase kernel, RESTORED (best residual:
// R7 178.5 vs R8 189.3). BM=256, BN=128, 512 thr (2Mx4N), 128x32/wave,
// acc[8][2]. B panel (WoT, 2MB) is L2-resident per XCD -> fill latency
// ~200cy -> 1-phase cover suffices; fine 2-phase with vmcnt(0) tops works.
// ---------------------------------------------------------------------------
__global__ __launch_bounds__(512) void gemm_out(
    const __bf16* __restrict__ A, const __bf16* __restrict__ Bt,
    float* __restrict__ outf, const float* __restrict__ bo)
{
    __shared__ __align__(16) __bf16 As[2][256][64];   // 64 KB
    __shared__ __align__(16) __bf16 Bs[2][128][64];   // 32 KB

    const int t = threadIdx.x;
    const int wave = t >> 6, lane = t & 63;
    const int quad = lane >> 4, l16 = lane & 15;
    const int wm = wave >> 2, wn = wave & 3;          // 2M x 4N waves

    const int nwg = gridDim.x * gridDim.y;            // 256
    const int cpx = nwg >> 3;
    int g = blockIdx.y * gridDim.x + blockIdx.x;
    g = (g & 7) * cpx + (g >> 3);
    const int bx = g % gridDim.x, by = g / gridDim.x;
    const int m0 = by * 256, n0 = bx * 128;

    const int srow = t >> 3;
    const int scol = (((t & 7) ^ (srow & 7)) * 8);
    const __bf16* pa = A  + (size_t)(m0 + srow) * 1024 + scol;
    const __bf16* pb = Bt + (size_t)(n0 + srow) * 1024 + scol;
    char* lA = (char*)(&As[0][0][0]) + t * 16;
    char* lB = (char*)(&Bs[0][0][0]) + t * 16;

#define SGA(slot, k0, c) gll16(pa + (k0) + (c) * 65536, lA + (slot) * 32768 + (c) * 8192)
#define SGB(slot, k0, c) gll16(pb + (k0) + (c) * 65536, lB + (slot) * 16384 + (c) * 8192)

    // Prologue: tile 0 -> slot 0, order E={a0,a2,b0,b1} then L={a1,a3}.
    SGA(0, 0, 0); SGA(0, 0, 2);
    SGB(0, 0, 0); SGB(0, 0, 1);
    SGA(0, 0, 1); SGA(0, 0, 3);

    f32x4 acc[8][2];
    #pragma unroll
    for (int i = 0; i < 8; ++i)
        #pragma unroll
        for (int j = 0; j < 2; ++j) acc[i][j] = (f32x4){0.f, 0.f, 0.f, 0.f};

    const int swz = (l16 & 7) << 4;

    asm volatile("s_waitcnt vmcnt(2)" ::: "memory");   // retire E_0
    __syncthreads();

    for (int it = 0; it < 16; ++it) {
        const int s = it & 1, ns = s ^ 1;
        const int kn = (it + 1) * 64;
        const bool st = (it < 15);
        const char* baseA = (const char*)&As[s][0][0];
        const char* baseB = (const char*)&Bs[s][0][0];

        bf16x8 af[4][2], b0f[2][2];

        // ---- ph0: retire L_it; read A-mh0 + B(all); stage E'(4) ----
        asm volatile("s_waitcnt vmcnt(0)" ::: "memory");
        #pragma unroll
        for (int mi = 0; mi < 4; ++mi) {
            int ra = (wm * 128 + mi * 16 + l16) * 128;
            af[mi][0] = *(const bf16x8*)(baseA + ra + ((quad * 16) ^ swz));
            af[mi][1] = *(const bf16x8*)(baseA + ra + ((64 + quad * 16) ^ swz));
        }
        #pragma unroll
        for (int nj = 0; nj < 2; ++nj) {
            int rb = (wn * 32 + nj * 16 + l16) * 128;
            b0f[nj][0] = *(const bf16x8*)(baseB + rb + ((quad * 16) ^ swz));
            b0f[nj][1] = *(const bf16x8*)(baseB + rb + ((64 + quad * 16) ^ swz));
        }
        if (st) { SGA(ns, kn, 0); SGA(ns, kn, 2); SGB(ns, kn, 0); SGB(ns, kn, 1); }
        __builtin_amdgcn_s_barrier();
        asm volatile("s_waitcnt lgkmcnt(0)" ::: "memory");
        __builtin_amdgcn_sched_barrier(0);
        __builtin_amdgcn_s_setprio(1);
        #pragma unroll
        for (int mi = 0; mi < 4; ++mi)
            #pragma unroll
            for (int nj = 0; nj < 2; ++nj)
                acc[mi][nj] = MFMA16(af[mi][1], b0f[nj][1],
                              MFMA16(af[mi][0], b0f[nj][0], acc[mi][nj]));
        __builtin_amdgcn_s_setprio(0);
        __builtin_amdgcn_s_barrier();

        // ---- ph1: retire E_{it+1}; read A-mh1; stage L'(2) ----
        asm volatile("s_waitcnt vmcnt(0)" ::: "memory");
        #pragma unroll
        for (int mi = 0; mi < 4; ++mi) {
            int ra = (wm * 128 + (4 + mi) * 16 + l16) * 128;
            af[mi][0] = *(const bf16x8*)(baseA + ra + ((quad * 16) ^ swz));
            af[mi][1] = *(const bf16x8*)(baseA + ra + ((64 + quad * 16) ^ swz));
        }
        if (st) { SGA(ns, kn, 1); SGA(ns, kn, 3); }
        __builtin_amdgcn_s_barrier();
        asm volatile("s_waitcnt lgkmcnt(0)" ::: "memory");
        __builtin_amdgcn_sched_barrier(0);
        __builtin_amdgcn_s_setprio(1);
        #pragma unroll
        for (int mi = 0; mi < 4; ++mi)
            #pragma unroll
            for (int nj = 0; nj < 2; ++nj)
                acc[4 + mi][nj] = MFMA16(af[mi][1], b0f[nj][1],
                                  MFMA16(af[mi][0], b0f[nj][0], acc[4 + mi][nj]));
        __builtin_amdgcn_s_setprio(0);
        __builtin_amdgcn_s_barrier();
    }
#undef SGA
#undef SGB

    #pragma unroll
    for (int mi = 0; mi < 8; ++mi) {
        int row = m0 + wm * 128 + mi * 16 + quad * 4;
        #pragma unroll
        for (int nj = 0; nj < 2; ++nj) {
            int n = n0 + wn * 32 + nj * 16 + l16;
            float bia = bo[n];
            #pragma unroll
            for (int r = 0; r < 4; ++r)
                outf[(size_t)(row + r) * 1024 + n] = acc[mi][nj][r] + bia;
        }
    }
}

// ---------------------------------------------------------------------------
// Flash attention. THIS ROUND: XCD-aware (bh,q0) remap. Previously the 8
// q-blocks sharing one head's 256KB K/V round-robined across XCDs -> every
// XCD pulled all 32MB of KV through its 4MB L2 -> HBM re-read x8 (~256MB).
// Remap gives XCD k heads [16k,16k+16): per-XCD KV working set = 4MB = L2.
// Bijection: id = by*128+bx; bh = (id&7)*16 + ((id>>3)&15); q0i = id>>7.
// Co-resident ids 0..511 cover q0i 0..3 of the same heads -> temporal reuse.
// Compute unchanged (fixed-base softmax, ping-pong K/V LDS, exp2, setprio).
// ---------------------------------------------------------------------------
__global__ __launch_bounds__(256) void attn(
    const __bf16* __restrict__ qb, const __bf16* __restrict__ kb,
    const __bf16* __restrict__ vb, const int* __restrict__ mask,
    __bf16* __restrict__ ctx)
{
    const int id = blockIdx.y * gridDim.x + blockIdx.x;   // gridDim.x = 128
    const int bh = (id & 7) * 16 + ((id >> 3) & 15);
    const int q0 = (id >> 7) * 128;
    const int b  = bh >> 4;
    const int h  = bh & 15;
    const size_t base = (size_t)bh * Ss * Kk;

    __shared__ __align__(16) __bf16 Qs[128][72];
    __shared__ __align__(16) __bf16 Ks[2][64][72];
    __shared__ __align__(16) __bf16 VTs[2][64][72];
    __shared__ __align__(16) __bf16 Ps[4][32][72];
    __shared__ float mkf[1024];

    const int t    = threadIdx.x;
    const int wave = t >> 6, lane = t & 63;
    const int quad = lane >> 4, l16 = lane & 15;
    const int qbase = wave * 32;

    #pragma unroll
    for (int p = 0; p < 4; ++p) {
        int idx = t + p * 256;
        int r = idx >> 3, gq = idx & 7;
        *(bf16x8*)&Qs[r][gq * 8] =
            *(const bf16x8*)(qb + base + (size_t)(q0 + r) * Kk + gq * 8);
    }
    {
        int4 mi = *(const int4*)(mask + b * Ss + t * 4);
        mkf[t * 4 + 0] = (float)mi.x;
        mkf[t * 4 + 1] = (float)mi.y;
        mkf[t * 4 + 2] = (float)mi.z;
        mkf[t * 4 + 3] = (float)mi.w;
    }

    const int r0 = t >> 3, c0 = (t & 7) * 8;
    bf16x8 kr0, kr1, vr0, vr1;
    kr0 = *(const bf16x8*)(kb + base + (size_t)(r0) * Kk + c0);
    kr1 = *(const bf16x8*)(kb + base + (size_t)(r0 + 32) * Kk + c0);
    vr0 = *(const bf16x8*)(vb + base + (size_t)(r0) * Ss + c0);
    vr1 = *(const bf16x8*)(vb + base + (size_t)(r0 + 32) * Ss + c0);

    __syncthreads();   // Qs + mkf visible

    bf16x8 aq[2][2];
    #pragma unroll
    for (int rg = 0; rg < 2; ++rg) {
        aq[rg][0] = *(const bf16x8*)&Qs[qbase + rg * 16 + l16][quad * 8];
        aq[rg][1] = *(const bf16x8*)&Qs[qbase + rg * 16 + l16][32 + quad * 8];
    }
    float mqf[2][4], omqf[2][4];
    #pragma unroll
    for (int rg = 0; rg < 2; ++rg)
        #pragma unroll
        for (int i = 0; i < 4; ++i) {
            float m = mkf[q0 + qbase + rg * 16 + quad * 4 + i];
            mqf[rg][i] = m; omqf[rg][i] = 1.0f - m;
        }

    f32x4 O[2][4];
    float lsum[2][4];
    #pragma unroll
    for (int rg = 0; rg < 2; ++rg)
        #pragma unroll
        for (int nb = 0; nb < 4; ++nb) O[rg][nb] = (f32x4){0.f, 0.f, 0.f, 0.f};
    #pragma unroll
    for (int rg = 0; rg < 2; ++rg)
        #pragma unroll
        for (int i = 0; i < 4; ++i) lsum[rg][i] = 0.f;

    for (int kt = 0; kt < Ss; kt += 64) {
        const int p = (kt >> 6) & 1;
        *(bf16x8*)&Ks[p][r0][c0] = kr0;
        *(bf16x8*)&Ks[p][r0 + 32][c0] = kr1;
        *(bf16x8*)&VTs[p][r0][c0] = vr0;
        *(bf16x8*)&VTs[p][r0 + 32][c0] = vr1;
        __syncthreads();   // the ONLY barrier per tile

        int ktn = kt + 64;
        if (ktn < Ss) {    // issue next tile's loads; in flight across compute
            kr0 = *(const bf16x8*)(kb + base + (size_t)(ktn + r0) * Kk + c0);
            kr1 = *(const bf16x8*)(kb + base + (size_t)(ktn + r0 + 32) * Kk + c0);
            vr0 = *(const bf16x8*)(vb + base + (size_t)(r0) * Ss + ktn + c0);
            vr1 = *(const bf16x8*)(vb + base + (size_t)(r0 + 32) * Ss + ktn + c0);
        }

        float mkv[4];
        #pragma unroll
        for (int nb = 0; nb < 4; ++nb) mkv[nb] = mkf[kt + nb * 16 + l16];

        bf16x8 kb0[4], kb1[4];
        #pragma unroll
        for (int nb = 0; nb < 4; ++nb) {
            kb0[nb] = *(const bf16x8*)&Ks[p][nb * 16 + l16][quad * 8];
            kb1[nb] = *(const bf16x8*)&Ks[p][nb * 16 + l16][32 + quad * 8];
        }

        f32x4 s[2][4];
        __builtin_amdgcn_s_setprio(1);
        #pragma unroll
        for (int rg = 0; rg < 2; ++rg)
            #pragma unroll
            for (int nb = 0; nb < 4; ++nb) {
                f32x4 a = (f32x4){0.f, 0.f, 0.f, 0.f};
                a = MFMA16(aq[rg][0], kb0[nb], a);
                a = MFMA16(aq[rg][1], kb1[nb], a);
                s[rg][nb] = a;
            }
        __builtin_amdgcn_s_setprio(0);

        #pragma unroll
        for (int rg = 0; rg < 2; ++rg)
            #pragma unroll
            for (int i = 0; i < 4; ++i) {
                float ls = 0.f;
                #pragma unroll
                for (int nb = 0; nb < 4; ++nb) {
                    float pv = exp2_hw(s[rg][nb][i]) * mkv[nb];
                    pv = pv * mqf[rg][i] + omqf[rg][i];
                    Ps[wave][rg * 16 + quad * 4 + i][nb * 16 + l16] = (__bf16)pv;
                    ls += pv;
                }
                lsum[rg][i] += ls;
            }

        bf16x8 ap0[2], ap1[2];
        #pragma unroll
        for (int rg = 0; rg < 2; ++rg) {
            ap0[rg] = *(const bf16x8*)&Ps[wave][rg * 16 + l16][quad * 8];
            ap1[rg] = *(const bf16x8*)&Ps[wave][rg * 16 + l16][32 + quad * 8];
        }
        __builtin_amdgcn_s_setprio(1);
        #pragma unroll
        for (int nb = 0; nb < 4; ++nb) {
            bf16x8 vb0 = *(const bf16x8*)&VTs[p][nb * 16 + l16][quad * 8];
            bf16x8 vb1 = *(const bf16x8*)&VTs[p][nb * 16 + l16][32 + quad * 8];
            #pragma unroll
            for (int rg = 0; rg < 2; ++rg) {
                O[rg][nb] = MFMA16(ap0[rg], vb0, O[rg][nb]);
                O[rg][nb] = MFMA16(ap1[rg], vb1, O[rg][nb]);
            }
        }
        __builtin_amdgcn_s_setprio(0);
    }

    #pragma unroll
    for (int rg = 0; rg < 2; ++rg)
        #pragma unroll
        for (int i = 0; i < 4; ++i) {
            float l = lsum[rg][i];
            l += __shfl_xor(l, 1);
            l += __shfl_xor(l, 2);
            l += __shfl_xor(l, 4);
            l += __shfl_xor(l, 8);
            float inv = 1.0f / l;
            int srow = q0 + qbase + rg * 16 + quad * 4 + i;
            __bf16* dst = ctx + ((size_t)(b * Ss + srow) * Hh + h) * Kk;
            #pragma unroll
            for (int nb = 0; nb < 4; ++nb)
                dst[nb * 16 + l16] = (__bf16)(O[rg][nb][i] * inv);
        }
}

extern "C" void kernel_launch(void* const* d_in, const int* in_sizes, int n_in,
                              void* d_out, int out_size, void* d_ws, size_t ws_size,
                              hipStream_t stream) {
    const float* x    = (const float*)d_in[0];
    const int*   mask = (const int*)d_in[1];
    const float* Wq   = (const float*)d_in[2];
    const float* bq   = (const float*)d_in[3];
    const float* Wk   = (const float*)d_in[4];
    const float* bk   = (const float*)d_in[5];
    const float* Wv   = (const float*)d_in[6];
    const float* bv   = (const float*)d_in[7];
    const float* Wo   = (const float*)d_in[8];
    const float* bo   = (const float*)d_in[9];

    __bf16* xb   = (__bf16*)d_ws;
    __bf16* WT   = xb + XB_E;
    __bf16* WoT  = WT + WT_E;
    __bf16* qb   = WoT + WOT_E;
    __bf16* kb   = qb + QKV_E;
    __bf16* vb   = kb + QKV_E;
    __bf16* ctxb = vb + QKV_E;
    float* out = (float*)d_out;

    prep<<<dim3(16, 16, 5), 256, 0, stream>>>(x, Wq, Wk, Wv, Wo, xb, WT, WoT);
    gemm_qkv<<<dim3(12, 32), 512, 0, stream>>>(xb, WT, qb, kb, vb, bq, bk, bv);
    attn<<<dim3(128, 8), 256, 0, stream>>>(qb, kb, vb, mask, ctxb);
    gemm_out<<<dim3(8, 32), 512, 0, stream>>>(ctxb, WoT, out, bo);
}

// Round 10
// 259.179 us; speedup vs baseline: 1.0256x; 1.0025x over previous
//
#include <hip/hip_runtime.h>
#include <math.h>

#define Ss 1024
#define Dd 1024
#define Hh 16
#define Kk 64

typedef __bf16 bf16x8 __attribute__((ext_vector_type(8)));
typedef __bf16 bf16x4 __attribute__((ext_vector_type(4)));
typedef float  f32x4  __attribute__((ext_vector_type(4)));

#define MFMA16(a, b, c) __builtin_amdgcn_mfma_f32_16x16x32_bf16(a, b, c, 0, 0, 0)

// ws element offsets (bf16 units)
#define XB_E   8388608u
#define WT_E   3145728u
#define WOT_E  1048576u
#define QKV_E  8388608u

// Q scale: (1/8) * log2(e) so attn can use raw v_exp_f32 (2^x).
#define QSC 0.18033688011112042f

// v_exp_f32 is natively 2^x; log2(e) is folded into the Q scale in gemm.
__device__ __forceinline__ float exp2_hw(float x) {
    float r; asm("v_exp_f32 %0, %1" : "=v"(r) : "v"(x)); return r;
}
// pack two f32 -> one u32 of 2 bf16 (lo = src0, hi = src1), RNE.
__device__ __forceinline__ unsigned cvtpk(float lo, float hi) {
    unsigned r;
    asm("v_cvt_pk_bf16_f32 %0, %1, %2" : "=v"(r) : "v"(lo), "v"(hi));
    return r;
}

// global -> LDS DMA, 16B per lane. LDS dest: wave-uniform base + lane*16.
typedef __attribute__((address_space(1))) const void gas_void;
typedef __attribute__((address_space(3))) void las_void;
__device__ __forceinline__ void gll16(const __bf16* g, char* l) {
    __builtin_amdgcn_global_load_lds((gas_void*)g, (las_void*)l, 16, 0, 0);
}

// ---------------------------------------------------------------------------
// prep: z<4 -> transpose+cast weight matrix z; z==4 -> cast x to bf16
// ---------------------------------------------------------------------------
__global__ __launch_bounds__(256) void prep(
    const float* __restrict__ x,
    const float* __restrict__ Wq, const float* __restrict__ Wk,
    const float* __restrict__ Wv, const float* __restrict__ Wo,
    __bf16* __restrict__ xb, __bf16* __restrict__ WT, __bf16* __restrict__ WoT)
{
    __shared__ float tile[64][65];
    const int z = blockIdx.z;
    const int t = threadIdx.x;

    if (z == 4) {   // x cast: 256 blocks, 32 rows x 1024 cols each
        size_t blk = blockIdx.y * 16 + blockIdx.x;
        const float4* src = (const float4*)(x + blk * 32768);
        bf16x4* dst = (bf16x4*)(((__bf16*)xb) + blk * 32768);
        #pragma unroll
        for (int u = 0; u < 32; ++u) {
            float4 v = src[u * 256 + t];
            dst[u * 256 + t] =
                (bf16x4){(__bf16)v.x, (__bf16)v.y, (__bf16)v.z, (__bf16)v.w};
        }
        return;
    }

    const float* src = (z == 0) ? Wq : (z == 1) ? Wk : (z == 2) ? Wv : Wo;
    __bf16* dst = (z < 3) ? (WT + (size_t)z * 1048576) : WoT;

    int r0 = blockIdx.y * 64, c0 = blockIdx.x * 64;
    int rr = t >> 2, cg = (t & 3) * 16;

    #pragma unroll
    for (int u = 0; u < 4; ++u) {
        float4 v = *(const float4*)(src + (size_t)(r0 + rr) * 1024 + c0 + cg + u * 4);
        tile[rr][cg + u * 4 + 0] = v.x;
        tile[rr][cg + u * 4 + 1] = v.y;
        tile[rr][cg + u * 4 + 2] = v.z;
        tile[rr][cg + u * 4 + 3] = v.w;
    }
    __syncthreads();
    bf16x8 o0, o1;
    #pragma unroll
    for (int jj = 0; jj < 8; ++jj) o0[jj] = (__bf16)tile[cg + jj][rr];
    #pragma unroll
    for (int jj = 0; jj < 8; ++jj) o1[jj] = (__bf16)tile[cg + 8 + jj][rr];
    __bf16* dp = dst + (size_t)(c0 + rr) * 1024 + r0 + cg;
    *(bf16x8*)dp = o0;
    *(bf16x8*)(dp + 8) = o1;
}

// ---------------------------------------------------------------------------
// QKV GEMM: measured-best (74.6-76.6 us), BANKED — do not touch.
// ---------------------------------------------------------------------------
__global__ __launch_bounds__(512, 2) void gemm_qkv(
    const __bf16* __restrict__ A, const __bf16* __restrict__ Bt,
    __bf16* __restrict__ qb, __bf16* __restrict__ kb, __bf16* __restrict__ vb,
    const float* __restrict__ bq, const float* __restrict__ bk,
    const float* __restrict__ bv)
{
    __shared__ __align__(16) __bf16 As[2][256][64];   // 64 KB
    __shared__ __align__(16) __bf16 Bs[2][256][64];   // 64 KB

    const int t = threadIdx.x;
    const int wave = t >> 6, lane = t & 63;
    const int quad = lane >> 4, l16 = lane & 15;
    const int wm = wave >> 2, wn = wave & 3;          // 2M x 4N waves

    const int nwg = gridDim.x * gridDim.y;
    const int cpx = nwg >> 3;
    int g = blockIdx.y * gridDim.x + blockIdx.x;
    g = (g & 7) * cpx + (g >> 3);
    const int bx = g % gridDim.x, by = g / gridDim.x;
    const int m0 = by * 256, n0 = bx * 256;

    const int srow = t >> 3;                              // 0..63
    const int scol = (((t & 7) ^ (srow & 7)) * 8);        // elems
    const __bf16* pa = A  + (size_t)(m0 + srow) * 1024 + scol;
    const __bf16* pb = Bt + (size_t)(n0 + srow) * 1024 + scol;
    char* lA = (char*)(&As[0][0][0]) + t * 16;
    char* lB = (char*)(&Bs[0][0][0]) + t * 16;

#define STAGE(slot, k0) do {                                     \
        gll16(pa + (k0),           lA + (slot) * 32768);         \
        gll16(pa + (k0) +  65536,  lA + (slot) * 32768 +  8192); \
        gll16(pa + (k0) + 131072,  lA + (slot) * 32768 + 16384); \
        gll16(pa + (k0) + 196608,  lA + (slot) * 32768 + 24576); \
        gll16(pb + (k0),           lB + (slot) * 32768);         \
        gll16(pb + (k0) +  65536,  lB + (slot) * 32768 +  8192); \
        gll16(pb + (k0) + 131072,  lB + (slot) * 32768 + 16384); \
        gll16(pb + (k0) + 196608,  lB + (slot) * 32768 + 24576); \
    } while (0)

    STAGE(0, 0);
    STAGE(1, 64);

    f32x4 acc[8][4];
    #pragma unroll
    for (int i = 0; i < 8; ++i)
        #pragma unroll
        for (int j = 0; j < 4; ++j) acc[i][j] = (f32x4){0.f, 0.f, 0.f, 0.f};

    const int swz = (l16 & 7) << 4;

    for (int it = 0; it < 16; ++it) {
        const int s = it & 1;
        if (it == 15) asm volatile("s_waitcnt vmcnt(0)" ::: "memory");
        else          asm volatile("s_waitcnt vmcnt(8)" ::: "memory");
        __builtin_amdgcn_s_barrier();                 // B1

        const char* baseA = (const char*)&As[s][0][0];
        const char* baseB = (const char*)&Bs[s][0][0];

        bf16x8 bfrag[2][4];
        #pragma unroll
        for (int nj = 0; nj < 4; ++nj) {
            int rowb = (wn * 64 + nj * 16 + l16) * 128;
            bfrag[0][nj] = *(const bf16x8*)(baseB + rowb + ((quad * 16) ^ swz));
            bfrag[1][nj] = *(const bf16x8*)(baseB + rowb + ((64 + quad * 16) ^ swz));
        }

        {
            bf16x8 afr[4][2];
            #pragma unroll
            for (int mi = 0; mi < 4; ++mi) {
                int rowa = (wm * 128 + mi * 16 + l16) * 128;
                afr[mi][0] = *(const bf16x8*)(baseA + rowa + ((quad * 16) ^ swz));
                afr[mi][1] = *(const bf16x8*)(baseA + rowa + ((64 + quad * 16) ^ swz));
            }
            __builtin_amdgcn_s_setprio(1);
            #pragma unroll
            for (int mi = 0; mi < 4; ++mi)
                #pragma unroll
                for (int nj = 0; nj < 4; ++nj)
                    acc[mi][nj] = MFMA16(afr[mi][1], bfrag[1][nj],
                                  MFMA16(afr[mi][0], bfrag[0][nj], acc[mi][nj]));
            __builtin_amdgcn_s_setprio(0);
        }
        __builtin_amdgcn_s_barrier();                 // B2 (rhythm)

        {
            bf16x8 afr[4][2];
            #pragma unroll
            for (int mi = 0; mi < 4; ++mi) {
                int rowa = (wm * 128 + (mi + 4) * 16 + l16) * 128;
                afr[mi][0] = *(const bf16x8*)(baseA + rowa + ((quad * 16) ^ swz));
                afr[mi][1] = *(const bf16x8*)(baseA + rowa + ((64 + quad * 16) ^ swz));
            }
            asm volatile("s_waitcnt lgkmcnt(0)" ::: "memory");
            __builtin_amdgcn_sched_barrier(0);
            __builtin_amdgcn_s_barrier();             // B3
            if (it < 14) STAGE(s, (it + 2) * 64);

            __builtin_amdgcn_s_setprio(1);
            #pragma unroll
            for (int mi = 0; mi < 4; ++mi)
                #pragma unroll
                for (int nj = 0; nj < 4; ++nj)
                    acc[mi + 4][nj] = MFMA16(afr[mi][1], bfrag[1][nj],
                                      MFMA16(afr[mi][0], bfrag[0][nj], acc[mi + 4][nj]));
            __builtin_amdgcn_s_setprio(0);
        }
    }
#undef STAGE

    {
        const int z = n0 >> 10;
        const float* bias = (z == 0) ? bq : (z == 1) ? bk : bv;
        const float sc2 = (z == 0) ? QSC : 1.0f;
        #pragma unroll
        for (int mi = 0; mi < 8; ++mi) {
            int row = m0 + wm * 128 + mi * 16 + quad * 4;
            int b = row >> 10, sx = row & 1023;
            #pragma unroll
            for (int nj = 0; nj < 4; ++nj) {
                int n1 = (n0 + wn * 64 + nj * 16 + l16) & 1023;
                int h = n1 >> 6, ch = n1 & 63;
                float bia = bias[n1];
                if (z < 2) {
                    __bf16* dst = ((z == 0) ? qb : kb)
                        + ((size_t)(b * Hh + h) * Ss + sx) * Kk + ch;
                    #pragma unroll
                    for (int r = 0; r < 4; ++r)
                        dst[(size_t)r * Kk] = (__bf16)((acc[mi][nj][r] + bia) * sc2);
                } else {
                    float bia2 = bv[n1];
                    bf16x4 o;
                    #pragma unroll
                    for (int r = 0; r < 4; ++r) o[r] = (__bf16)(acc[mi][nj][r] + bia2);
                    *(bf16x4*)(vb + ((size_t)(b * Hh + h) * Kk + ch) * Ss + sx) = o;
                }
            }
        }
    }
}

// ---------------------------------------------------------------------------
// Out-GEMM: R7 fine-grained 2-phase (best residual), BANKED.
// ---------------------------------------------------------------------------
__global__ __launch_bounds__(512) void gemm_out(
    const __bf16* __restrict__ A, const __bf16* __restrict__ Bt,
    float* __restrict__ outf, const float* __restrict__ bo)
{
    __shared__ __align__(16) __bf16 As[2][256][64];   // 64 KB
    __shared__ __align__(16) __bf16 Bs[2][128][64];   // 32 KB

    const int t = threadIdx.x;
    const int wave = t >> 6, lane = t & 63;
    const int quad = lane >> 4, l16 = lane & 15;
    const int wm = wave >> 2, wn = wave & 3;

    const int nwg = gridDim.x * gridDim.y;            // 256
    const int cpx = nwg >> 3;
    int g = blockIdx.y * gridDim.x + blockIdx.x;
    g = (g & 7) * cpx + (g >> 3);
    const int bx = g % gridDim.x, by = g / gridDim.x;
    const int m0 = by * 256, n0 = bx * 128;

    const int srow = t >> 3;
    const int scol = (((t & 7) ^ (srow & 7)) * 8);
    const __bf16* pa = A  + (size_t)(m0 + srow) * 1024 + scol;
    const __bf16* pb = Bt + (size_t)(n0 + srow) * 1024 + scol;
    char* lA = (char*)(&As[0][0][0]) + t * 16;
    char* lB = (char*)(&Bs[0][0][0]) + t * 16;

#define SGA(slot, k0, c) gll16(pa + (k0) + (c) * 65536, lA + (slot) * 32768 + (c) * 8192)
#define SGB(slot, k0, c) gll16(pb + (k0) + (c) * 65536, lB + (slot) * 16384 + (c) * 8192)

    SGA(0, 0, 0); SGA(0, 0, 2);
    SGB(0, 0, 0); SGB(0, 0, 1);
    SGA(0, 0, 1); SGA(0, 0, 3);

    f32x4 acc[8][2];
    #pragma unroll
    for (int i = 0; i < 8; ++i)
        #pragma unroll
        for (int j = 0; j < 2; ++j) acc[i][j] = (f32x4){0.f, 0.f, 0.f, 0.f};

    const int swz = (l16 & 7) << 4;

    asm volatile("s_waitcnt vmcnt(2)" ::: "memory");
    __syncthreads();

    for (int it = 0; it < 16; ++it) {
        const int s = it & 1, ns = s ^ 1;
        const int kn = (it + 1) * 64;
        const bool st = (it < 15);
        const char* baseA = (const char*)&As[s][0][0];
        const char* baseB = (const char*)&Bs[s][0][0];

        bf16x8 af[4][2], b0f[2][2];

        asm volatile("s_waitcnt vmcnt(0)" ::: "memory");
        #pragma unroll
        for (int mi = 0; mi < 4; ++mi) {
            int ra = (wm * 128 + mi * 16 + l16) * 128;
            af[mi][0] = *(const bf16x8*)(baseA + ra + ((quad * 16) ^ swz));
            af[mi][1] = *(const bf16x8*)(baseA + ra + ((64 + quad * 16) ^ swz));
        }
        #pragma unroll
        for (int nj = 0; nj < 2; ++nj) {
            int rb = (wn * 32 + nj * 16 + l16) * 128;
            b0f[nj][0] = *(const bf16x8*)(baseB + rb + ((quad * 16) ^ swz));
            b0f[nj][1] = *(const bf16x8*)(baseB + rb + ((64 + quad * 16) ^ swz));
        }
        if (st) { SGA(ns, kn, 0); SGA(ns, kn, 2); SGB(ns, kn, 0); SGB(ns, kn, 1); }
        __builtin_amdgcn_s_barrier();
        asm volatile("s_waitcnt lgkmcnt(0)" ::: "memory");
        __builtin_amdgcn_sched_barrier(0);
        __builtin_amdgcn_s_setprio(1);
        #pragma unroll
        for (int mi = 0; mi < 4; ++mi)
            #pragma unroll
            for (int nj = 0; nj < 2; ++nj)
                acc[mi][nj] = MFMA16(af[mi][1], b0f[nj][1],
                              MFMA16(af[mi][0], b0f[nj][0], acc[mi][nj]));
        __builtin_amdgcn_s_setprio(0);
        __builtin_amdgcn_s_barrier();

        asm volatile("s_waitcnt vmcnt(0)" ::: "memory");
        #pragma unroll
        for (int mi = 0; mi < 4; ++mi) {
            int ra = (wm * 128 + (4 + mi) * 16 + l16) * 128;
            af[mi][0] = *(const bf16x8*)(baseA + ra + ((quad * 16) ^ swz));
            af[mi][1] = *(const bf16x8*)(baseA + ra + ((64 + quad * 16) ^ swz));
        }
        if (st) { SGA(ns, kn, 1); SGA(ns, kn, 3); }
        __builtin_amdgcn_s_barrier();
        asm volatile("s_waitcnt lgkmcnt(0)" ::: "memory");
        __builtin_amdgcn_sched_barrier(0);
        __builtin_amdgcn_s_setprio(1);
        #pragma unroll
        for (int mi = 0; mi < 4; ++mi)
            #pragma unroll
            for (int nj = 0; nj < 2; ++nj)
                acc[4 + mi][nj] = MFMA16(af[mi][1], b0f[nj][1],
                                  MFMA16(af[mi][0], b0f[nj][0], acc[4 + mi][nj]));
        __builtin_amdgcn_s_setprio(0);
        __builtin_amdgcn_s_barrier();
    }
#undef SGA
#undef SGB

    #pragma unroll
    for (int mi = 0; mi < 8; ++mi) {
        int row = m0 + wm * 128 + mi * 16 + quad * 4;
        #pragma unroll
        for (int nj = 0; nj < 2; ++nj) {
            int n = n0 + wn * 32 + nj * 16 + l16;
            float bia = bo[n];
            #pragma unroll
            for (int r = 0; r < 4; ++r)
                outf[(size_t)(row + r) * 1024 + n] = acc[mi][nj][r] + bia;
        }
    }
}

// ---------------------------------------------------------------------------
// Flash attention v2: IN-REGISTER P (no Ps/Qs LDS).
// - Swapped QK^T: MFMA16(K-frag, Q-frag) -> P'[k][q], q = l16 lane-local.
//   (operand fragments identical to v1; only argument order changes)
// - Softmax per-lane on 16 held P-values; mask: mk per-(nb,quad,i) via
//   float4 LDS loads, mq one scalar per rg. lsum reduce = shfl_xor(16,32).
// - P -> PV B-frag via v_cvt_pk_bf16_f32 + 8 shuffles per (rg,m):
//   dest (quad,l16) frag elem j (k'=32m+8*quad+j) comes from src lane
//   ((quad&1)<<5)|l16 (+16 for j>=4), reg pk[2m+(quad>>1)][(j&3)>>1].
// - PV swapped: O^T = MFMA16(V-frag, P-frag); V-frag reads unchanged.
// - Output: O^T[ch][q]: 8x bf16x4 stores per thread.
// - LDS 40 KB (Ks+VTs+mkf) -> __launch_bounds__(256,3): 3 blocks/CU target.
// Mask semantics: p = e*mk*mq + (1-mq) — exactly matches reference.
// ---------------------------------------------------------------------------
__global__ __launch_bounds__(256, 3) void attn(
    const __bf16* __restrict__ qb, const __bf16* __restrict__ kb,
    const __bf16* __restrict__ vb, const int* __restrict__ mask,
    __bf16* __restrict__ ctx)
{
    const int bh = blockIdx.x;
    const int q0 = blockIdx.y * 128;
    const int b  = bh >> 4;
    const int h  = bh & 15;
    const size_t base = (size_t)bh * Ss * Kk;

    __shared__ __align__(16) __bf16 Ks[2][64][72];
    __shared__ __align__(16) __bf16 VTs[2][64][72];
    __shared__ float mkf[1024];

    const int t    = threadIdx.x;
    const int wave = t >> 6, lane = t & 63;
    const int quad = lane >> 4, l16 = lane & 15;
    const int qbase = wave * 32;

    {
        int4 mi = *(const int4*)(mask + b * Ss + t * 4);
        mkf[t * 4 + 0] = (float)mi.x;
        mkf[t * 4 + 1] = (float)mi.y;
        mkf[t * 4 + 2] = (float)mi.z;
        mkf[t * 4 + 3] = (float)mi.w;
    }

    const int r0 = t >> 3, c0 = (t & 7) * 8;
    bf16x8 kr0, kr1, vr0, vr1;
    kr0 = *(const bf16x8*)(kb + base + (size_t)(r0) * Kk + c0);
    kr1 = *(const bf16x8*)(kb + base + (size_t)(r0 + 32) * Kk + c0);
    vr0 = *(const bf16x8*)(vb + base + (size_t)(r0) * Ss + c0);
    vr1 = *(const bf16x8*)(vb + base + (size_t)(r0 + 32) * Ss + c0);

    // Q-fragments straight from global (no LDS stage): lane needs
    // Q[qbase+rg*16+l16][quad*8+j (+32)], 16B per load.
    bf16x8 aq[2][2];
    #pragma unroll
    for (int rg = 0; rg < 2; ++rg) {
        const __bf16* qrow = qb + base + (size_t)(q0 + qbase + rg * 16 + l16) * Kk;
        aq[rg][0] = *(const bf16x8*)(qrow + quad * 8);
        aq[rg][1] = *(const bf16x8*)(qrow + 32 + quad * 8);
    }

    __syncthreads();   // mkf visible

    float mq[2], omq[2];
    #pragma unroll
    for (int rg = 0; rg < 2; ++rg) {
        float m_ = mkf[q0 + qbase + rg * 16 + l16];
        mq[rg] = m_; omq[rg] = 1.0f - m_;
    }

    f32x4 O[2][4];
    float lsum[2] = {0.f, 0.f};
    #pragma unroll
    for (int rg = 0; rg < 2; ++rg)
        #pragma unroll
        for (int nb = 0; nb < 4; ++nb) O[rg][nb] = (f32x4){0.f, 0.f, 0.f, 0.f};

    const int SA = ((quad & 1) << 5) | l16;   // shuffle sources
    const int SB = SA + 16;
    const bool hi = (quad >> 1) != 0;

    for (int kt = 0; kt < Ss; kt += 64) {
        const int p = (kt >> 6) & 1;
        *(bf16x8*)&Ks[p][r0][c0] = kr0;
        *(bf16x8*)&Ks[p][r0 + 32][c0] = kr1;
        *(bf16x8*)&VTs[p][r0][c0] = vr0;
        *(bf16x8*)&VTs[p][r0 + 32][c0] = vr1;
        __syncthreads();   // the ONLY barrier per tile

        int ktn = kt + 64;
        if (ktn < Ss) {    // next tile's loads in flight across compute
            kr0 = *(const bf16x8*)(kb + base + (size_t)(ktn + r0) * Kk + c0);
            kr1 = *(const bf16x8*)(kb + base + (size_t)(ktn + r0 + 32) * Kk + c0);
            vr0 = *(const bf16x8*)(vb + base + (size_t)(r0) * Ss + ktn + c0);
            vr1 = *(const bf16x8*)(vb + base + (size_t)(r0 + 32) * Ss + ktn + c0);
        }

        // K-fragments (same reads as v1)
        bf16x8 kb0[4], kb1[4];
        #pragma unroll
        for (int nb = 0; nb < 4; ++nb) {
            kb0[nb] = *(const bf16x8*)&Ks[p][nb * 16 + l16][quad * 8];
            kb1[nb] = *(const bf16x8*)&Ks[p][nb * 16 + l16][32 + quad * 8];
        }

        // Swapped QK^T: s[rg][nb] = P'[k-block nb][q=l16]
        f32x4 s[2][4];
        __builtin_amdgcn_s_setprio(1);
        #pragma unroll
        for (int rg = 0; rg < 2; ++rg)
            #pragma unroll
            for (int nb = 0; nb < 4; ++nb) {
                f32x4 a = (f32x4){0.f, 0.f, 0.f, 0.f};
                a = MFMA16(kb0[nb], aq[rg][0], a);
                a = MFMA16(kb1[nb], aq[rg][1], a);
                s[rg][nb] = a;
            }
        __builtin_amdgcn_s_setprio(0);

        // V-fragments (same reads as v1's vb0/vb1), shared by both rg
        bf16x8 vbf0[4], vbf1[4];
        #pragma unroll
        for (int nb = 0; nb < 4; ++nb) {
            vbf0[nb] = *(const bf16x8*)&VTs[p][nb * 16 + l16][quad * 8];
            vbf1[nb] = *(const bf16x8*)&VTs[p][nb * 16 + l16][32 + quad * 8];
        }

        #pragma unroll
        for (int rg = 0; rg < 2; ++rg) {
            // softmax in-register: lane holds P'[k=16nb+4quad+i][q=l16]
            float ls = 0.f;
            unsigned pk[4][2];
            #pragma unroll
            for (int nb = 0; nb < 4; ++nb) {
                float4 mk4 = *(const float4*)&mkf[kt + nb * 16 + quad * 4];
                #pragma unroll
                for (int i = 0; i < 4; ++i) {
                    float e = exp2_hw(s[rg][nb][i]);
                    float pv = e * ((const float*)&mk4)[i] * mq[rg] + omq[rg];
                    s[rg][nb][i] = pv;
                    ls += pv;
                }
                pk[nb][0] = cvtpk(s[rg][nb][0], s[rg][nb][1]);
                pk[nb][1] = cvtpk(s[rg][nb][2], s[rg][nb][3]);
            }
            lsum[rg] += ls;

            // PV: per m (k 32m..32m+31) build B-frag by shuffle, then MFMA
            #pragma unroll
            for (int m = 0; m < 2; ++m) {
                unsigned a0 = (unsigned)__shfl((int)pk[2 * m][0], SA);
                unsigned b0 = (unsigned)__shfl((int)pk[2 * m + 1][0], SA);
                unsigned a1 = (unsigned)__shfl((int)pk[2 * m][1], SA);
                unsigned b1 = (unsigned)__shfl((int)pk[2 * m + 1][1], SA);
                unsigned a2 = (unsigned)__shfl((int)pk[2 * m][0], SB);
                unsigned b2 = (unsigned)__shfl((int)pk[2 * m + 1][0], SB);
                unsigned a3 = (unsigned)__shfl((int)pk[2 * m][1], SB);
                unsigned b3 = (unsigned)__shfl((int)pk[2 * m + 1][1], SB);
                union { unsigned u[4]; bf16x8 v; } bb;
                bb.u[0] = hi ? b0 : a0;
                bb.u[1] = hi ? b1 : a1;
                bb.u[2] = hi ? b2 : a2;
                bb.u[3] = hi ? b3 : a3;
                __builtin_amdgcn_s_setprio(1);
                #pragma unroll
                for (int nb = 0; nb < 4; ++nb)
                    O[rg][nb] = MFMA16(m ? vbf1[nb] : vbf0[nb], bb.v, O[rg][nb]);
                __builtin_amdgcn_s_setprio(0);
            }
        }
    }

    // Epilogue: O^T[ch = nb*16+quad*4+i][q = l16]; lsum reduce across quads.
    #pragma unroll
    for (int rg = 0; rg < 2; ++rg) {
        float l = lsum[rg];
        l += __shfl_xor(l, 16);
        l += __shfl_xor(l, 32);
        float inv = 1.0f / l;
        int srow = q0 + qbase + rg * 16 + l16;
        __bf16* dst = ctx + ((size_t)(b * Ss + srow) * Hh + h) * Kk;
        #pragma unroll
        for (int nb = 0; nb < 4; ++nb) {
            bf16x4 o;
            #pragma unroll
            for (int i = 0; i < 4; ++i) o[i] = (__bf16)(O[rg][nb][i] * inv);
            *(bf16x4*)(dst + nb * 16 + quad * 4) = o;
        }
    }
}

extern "C" void kernel_launch(void* const* d_in, const int* in_sizes, int n_in,
                              void* d_out, int out_size, void* d_ws, size_t ws_size,
                              hipStream_t stream) {
    const float* x    = (const float*)d_in[0];
    const int*   mask = (const int*)d_in[1];
    const float* Wq   = (const float*)d_in[2];
    const float* bq   = (const float*)d_in[3];
    const float* Wk   = (const float*)d_in[4];
    const float* bk   = (const float*)d_in[5];
    const float* Wv   = (const float*)d_in[6];
    const float* bv   = (const float*)d_in[7];
    const float* Wo   = (const float*)d_in[8];
    const float* bo   = (const float*)d_in[9];

    __bf16* xb   = (__bf16*)d_ws;
    __bf16* WT   = xb + XB_E;
    __bf16* WoT  = WT + WT_E;
    __bf16* qb   = WoT + WOT_E;
    __bf16* kb   = qb + QKV_E;
    __bf16* vb   = kb + QKV_E;
    __bf16* ctxb = vb + QKV_E;
    float* out = (float*)d_out;

    prep<<<dim3(16, 16, 5), 256, 0, stream>>>(x, Wq, Wk, Wv, Wo, xb, WT, WoT);
    gemm_qkv<<<dim3(12, 32), 512, 0, stream>>>(xb, WT, qb, kb, vb, bq, bk, bv);
    attn<<<dim3(128, 8), 256, 0, stream>>>(qb, kb, vb, mask, ctxb);
    gemm_out<<<dim3(8, 32), 512, 0, stream>>>(ctxb, WoT, out, bo);
}